// Round 2
// baseline (133.555 us; speedup 1.0000x reference)
//
#include <hip/hip_runtime.h>

// VarlenAttention MI355X — round 7: two-kernel (bf16 prepass + attn) with
// (a) LPT work-ranked block mapping: blocks pick their q-tile by sorted
//     k-span rank so heavy tiles spread across all CUs (fixes 16% occupancy
//     load-imbalance tail),
// (b) un-padded XOR-swizzled LDS (slot ^= row&7): all ds_read_b128 operand
//     reads and staging writes become <=2-way (was ~8-way at stride-144B,
//     SQ_LDS_BANK_CONFLICT 2.49M),
// (c) 24.6KB LDS, single-buffered with register prefetch -> all 768 blocks
//     co-resident (capacity 6 blocks/CU), barriers skipped on last chunk.
// r6 post-mortem: harness fill/restore overhead ~75.5us is constant whether
// or not ws is used; prepass is ~3us; fused in-loop conversion cost 9us.
constexpr int NSEG = 8;
constexpr int H    = 16;
constexpr int D    = 64;
constexpr int BK   = 64;
constexpr int LDKP = D + 8;   // prepass-only padded layout

typedef __attribute__((ext_vector_type(8))) short short8v;
typedef __attribute__((ext_vector_type(4))) short short4v;
typedef __attribute__((ext_vector_type(4))) float floatx4;

__device__ inline short f2bf(float f) {  // RNE fp32 -> bf16
    union { float f; unsigned u; } x; x.f = f;
    unsigned r = x.u + 0x7FFFu + ((x.u >> 16) & 1u);
    return (short)(r >> 16);
}

// ---------------- pre-pass: Kb[h][t][d], Vb[h][d][t], segArr[t] -------------
__global__ __launch_bounds__(256)
void prepass_kv(const float* __restrict__ K, const float* __restrict__ V,
                const int* __restrict__ cuk,
                short* __restrict__ Kb, short* __restrict__ Vb,
                int* __restrict__ segArr, int T)
{
    __shared__ short sVT[D][LDKP];
    const int tid = threadIdx.x;
    const int nCh = T >> 6;
    const int h  = blockIdx.x / nCh;
    const int t0 = (blockIdx.x % nCh) << 6;
    #pragma unroll
    for (int it = 0; it < 2; ++it) {
        int s  = tid + it * 256;
        int tl = s >> 3;
        int d8 = (s & 7) << 3;
        int t  = t0 + tl;
        const float* kp = K + ((size_t)t * H + h) * D + d8;
        float4 a = *(const float4*)kp;
        float4 b = *(const float4*)(kp + 4);
        short8v ks;
        ks[0]=f2bf(a.x); ks[1]=f2bf(a.y); ks[2]=f2bf(a.z); ks[3]=f2bf(a.w);
        ks[4]=f2bf(b.x); ks[5]=f2bf(b.y); ks[6]=f2bf(b.z); ks[7]=f2bf(b.w);
        *(short8v*)&Kb[((size_t)h * T + t) * D + d8] = ks;
        const float* vp = V + ((size_t)t * H + h) * D + d8;
        float4 c = *(const float4*)vp;
        float4 e = *(const float4*)(vp + 4);
        sVT[d8+0][tl]=f2bf(c.x); sVT[d8+1][tl]=f2bf(c.y);
        sVT[d8+2][tl]=f2bf(c.z); sVT[d8+3][tl]=f2bf(c.w);
        sVT[d8+4][tl]=f2bf(e.x); sVT[d8+5][tl]=f2bf(e.y);
        sVT[d8+6][tl]=f2bf(e.z); sVT[d8+7][tl]=f2bf(e.w);
    }
    if (h == 0 && tid < 64) {
        int t = t0 + tid;
        int s = 0;
        #pragma unroll
        for (int i = 1; i < NSEG; ++i) s += (t >= cuk[i]) ? 1 : 0;
        segArr[t] = s;
    }
    __syncthreads();
    #pragma unroll
    for (int it = 0; it < 2; ++it) {
        int s  = tid + it * 256;
        int d  = s >> 3;
        int t8 = (s & 7) << 3;
        *(short8v*)&Vb[((size_t)h * D + d) * T + t0 + t8] = *(const short8v*)&sVT[d][t8];
    }
}

// ---------------- main: LPT-ranked, swizzled-LDS flash ----------------------
__global__ __launch_bounds__(256, 3)
void varlen_attn7(const float* __restrict__ Q,
                  const short* __restrict__ Kb, const short* __restrict__ Vb,
                  const int* __restrict__ segArr,
                  const int* __restrict__ cuq, const int* __restrict__ cuk,
                  float* __restrict__ O, int T)
{
    // un-padded, XOR-swizzled (element [row][s*8+e] lives at
    // [(row][( s ^ (row&7) )*8 + e]).  24.6 KB -> 6 blocks/CU capacity,
    // grid (<=1024 blocks) fully co-resident.
    __shared__ short sK [BK][D];    // (key, d)
    __shared__ short sVT[D][BK];    // (d, key)
    __shared__ short sP [4][16][BK];

    const int tid  = threadIdx.x;
    const int lane = tid & 63;
    const int w    = tid >> 6;
    const int quad = lane >> 4;
    const int l15  = lane & 15;

    const int q1 = cuq[1], q2 = cuq[2], q3 = cuq[3], q4 = cuq[4],
              q5 = cuq[5], q6 = cuq[6], q7 = cuq[7];
    const int c0 = cuk[0], c1 = cuk[1], c2 = cuk[2], c3 = cuk[3], c4 = cuk[4],
              c5 = cuk[5], c6 = cuk[6], c7 = cuk[7], c8 = cuk[8];

    auto segOf = [&](int t) {
        return (t>=q1)+(t>=q2)+(t>=q3)+(t>=q4)+(t>=q5)+(t>=q6)+(t>=q7);
    };
    auto ksOf = [&](int s) {
        int k = c0;
        k=(s>0)?c1:k; k=(s>1)?c2:k; k=(s>2)?c3:k; k=(s>3)?c4:k;
        k=(s>4)?c5:k; k=(s>5)?c6:k; k=(s>6)?c7:k;
        return k;
    };
    auto keOf = [&](int s) {
        int k = c1;
        k=(s>0)?c2:k; k=(s>1)?c3:k; k=(s>2)?c4:k; k=(s>3)?c5:k;
        k=(s>4)?c6:k; k=(s>5)?c7:k; k=(s>6)?c8:k;
        return k;
    };

    // ---- LPT mapping: lane j scores q-block j by its k-span; rank desc.
    // blockIdx = rank*H + head  ->  heavy q-blocks spread over all CUs/XCDs.
    const int nQB = T >> 6;            // main path guarantees nQB <= 64
    int qb;
    {
        int j  = lane;
        int wj = -1;
        if (j < nQB) {
            int tA = j << 6;
            wj = keOf(segOf(tA + 63)) - ksOf(segOf(tA));
        }
        int rank = 0;
        for (int i = 0; i < nQB; ++i) {
            int wi = __shfl(wj, i);
            rank += (wi > wj || (wi == wj && i < j)) ? 1 : 0;
        }
        const int krank = blockIdx.x >> 4;
        unsigned long long m = __ballot(j < nQB && rank == krank);
        qb = (int)__builtin_ctzll(m);
    }
    const int t0 = qb << 6;
    const int h  = blockIdx.x & (H - 1);

    // Q A-fragments, pre-scaled by (1/8)*log2(e); C-init carries -8*log2(e)
    // so softmax is a bare v_exp_f32 (exp2), masked lanes -> exactly 0.
    const float SC = 0.125f * 1.44269504f;
    const float* qp = Q + ((size_t)(t0 + 16 * w + l15) * H + h) * D + quad * 8;
    short8v aQ0, aQ1;
    {
        float4 a = *(const float4*)(qp);
        float4 b = *(const float4*)(qp + 4);
        float4 c = *(const float4*)(qp + 32);
        float4 e = *(const float4*)(qp + 36);
        aQ0[0]=f2bf(a.x*SC); aQ0[1]=f2bf(a.y*SC); aQ0[2]=f2bf(a.z*SC); aQ0[3]=f2bf(a.w*SC);
        aQ0[4]=f2bf(b.x*SC); aQ0[5]=f2bf(b.y*SC); aQ0[6]=f2bf(b.z*SC); aQ0[7]=f2bf(b.w*SC);
        aQ1[0]=f2bf(c.x*SC); aQ1[1]=f2bf(c.y*SC); aQ1[2]=f2bf(c.z*SC); aQ1[3]=f2bf(c.w*SC);
        aQ1[4]=f2bf(e.x*SC); aQ1[5]=f2bf(e.y*SC); aQ1[6]=f2bf(e.z*SC); aQ1[7]=f2bf(e.w*SC);
    }

    int segq[4];
    #pragma unroll
    for (int r = 0; r < 4; ++r)
        segq[r] = segOf(t0 + 16 * w + quad * 4 + r);
    const int k_start = ksOf(segOf(t0));
    const int k_end   = keOf(segOf(t0 + 63));

    const short* Kbh = Kb + (size_t)h * T * D;
    const short* Vbh = Vb + (size_t)h * D * T;
    const int key0 = tid >> 3;                       // 0..31
    const int e8   = (tid & 7) << 3;                 // 0..56
    const int slA  = (((tid & 7) ^ (key0 & 7)) << 3);  // swizzled write slot
    const int sw3  = (l15 & 7) << 3;                 // swizzled read offset

    short8v rk0, rk1, rv0, rv1;
    int sgC[4], sgN[4];

    auto LOADC = [&](int kc_) {   // register prefetch of chunk kc_
        rk0 = *(const short8v*)(Kbh + (size_t)(kc_ + key0)      * D + e8);
        rk1 = *(const short8v*)(Kbh + (size_t)(kc_ + 32 + key0) * D + e8);
        rv0 = *(const short8v*)(Vbh + (size_t)key0        * T + kc_ + e8);
        rv1 = *(const short8v*)(Vbh + (size_t)(32 + key0) * T + kc_ + e8);
        #pragma unroll
        for (int nt = 0; nt < 4; ++nt) sgN[nt] = segArr[kc_ + nt * 16 + l15];
    };
    auto WRITEC = [&]() {         // regs -> swizzled LDS
        *(short8v*)&sK [key0     ][slA] = rk0;
        *(short8v*)&sK [key0 + 32][slA] = rk1;     // (key0+32)&7 == key0&7
        *(short8v*)&sVT[key0     ][slA] = rv0;
        *(short8v*)&sVT[key0 + 32][slA] = rv1;
    };

    floatx4 o[4];
    #pragma unroll
    for (int nt = 0; nt < 4; ++nt) o[nt] = (floatx4){0.f, 0.f, 0.f, 0.f};
    float l_r[4] = {0.f, 0.f, 0.f, 0.f};

    const float C0 = -11.54156032f;   // -8 * log2(e)
    const int kc0 = k_start & ~(BK - 1);

    LOADC(kc0);
    #pragma unroll
    for (int nt = 0; nt < 4; ++nt) sgC[nt] = sgN[nt];
    WRITEC();
    __syncthreads();

    for (int kc = kc0; kc < k_end; kc += BK) {
        const bool more = (kc + BK) < k_end;        // block-uniform
        if (more) LOADC(kc + BK);                   // covered by compute below

        // ---- S' = (Q*log2e) K^T - 8*log2e ----
        floatx4 sacc[4];
        #pragma unroll
        for (int nt = 0; nt < 4; ++nt) {
            const short* kr = &sK[nt * 16 + l15][0];
            short8v b0 = *(const short8v*)(kr + (( quad      << 3) ^ sw3));
            short8v b1 = *(const short8v*)(kr + (((quad + 4) << 3) ^ sw3));
            sacc[nt] = (floatx4){C0, C0, C0, C0};
            sacc[nt] = __builtin_amdgcn_mfma_f32_16x16x32_bf16(aQ0, b0, sacc[nt], 0, 0, 0);
            sacc[nt] = __builtin_amdgcn_mfma_f32_16x16x32_bf16(aQ1, b1, sacc[nt], 0, 0, 0);
        }

        // ---- mask + exp2, write P to wave-private swizzled LDS ----
        #pragma unroll
        for (int nt = 0; nt < 4; ++nt) {
            #pragma unroll
            for (int r = 0; r < 4; ++r) {
                float sc = (sgC[nt] == segq[r]) ? sacc[nt][r] : -1e30f;
                float p  = __builtin_amdgcn_exp2f(sc);
                l_r[r] += p;
                int row = quad * 4 + r;
                int col = (((nt * 2 + (l15 >> 3)) ^ (row & 7)) << 3) + (l15 & 7);
                sP[w][row][col] = f2bf(p);
            }
        }

        // ---- P: C-layout -> A-layout (wave-private roundtrip) ----
        const short* pr = &sP[w][l15][0];
        short8v aP0 = *(const short8v*)(pr + (( quad      << 3) ^ sw3));
        short8v aP1 = *(const short8v*)(pr + (((quad + 4) << 3) ^ sw3));

        // ---- O += P V ----
        #pragma unroll
        for (int nt = 0; nt < 4; ++nt) {
            const short* vr = &sVT[nt * 16 + l15][0];
            short8v b0 = *(const short8v*)(vr + (( quad      << 3) ^ sw3));
            short8v b1 = *(const short8v*)(vr + (((quad + 4) << 3) ^ sw3));
            o[nt] = __builtin_amdgcn_mfma_f32_16x16x32_bf16(aP0, b0, o[nt], 0, 0, 0);
            o[nt] = __builtin_amdgcn_mfma_f32_16x16x32_bf16(aP1, b1, o[nt], 0, 0, 0);
        }

        if (more) {
            __syncthreads();      // all waves done reading sK/sVT
            WRITEC();
            #pragma unroll
            for (int nt = 0; nt < 4; ++nt) sgC[nt] = sgN[nt];
            __syncthreads();      // next chunk visible
        }
    }

    // ---- epilogue: 16-lane reduction of l, normalize, store ----
    #pragma unroll
    for (int off = 1; off < 16; off <<= 1)
        #pragma unroll
        for (int r = 0; r < 4; ++r)
            l_r[r] += __shfl_xor(l_r[r], off);

    #pragma unroll
    for (int r = 0; r < 4; ++r) {
        int trow = t0 + 16 * w + quad * 4 + r;
        float linv = 1.0f / l_r[r];
        float* op = O + ((size_t)trow * H + h) * D + l15;
        #pragma unroll
        for (int nt = 0; nt < 4; ++nt)
            op[nt * 16] = o[nt][r] * linv;
    }
}

// ---------------- fallback (self-contained, any T) --------------------------
__global__ __launch_bounds__(256)
void varlen_attn_fb(const float* __restrict__ Q, const float* __restrict__ K,
                    const float* __restrict__ V, const int* __restrict__ cuq,
                    const int* __restrict__ cuk, float* __restrict__ O, int T)
{
    __shared__ short sK[BK][LDKP];
    __shared__ short sVT[D][BK + 8];
    __shared__ short sP[4][16][BK + 8];
    __shared__ int   sSegK[BK];
    __shared__ int   sCuQ[NSEG + 1], sCuK[NSEG + 1];

    const int tid  = threadIdx.x;
    const int lane = tid & 63;
    const int w    = tid >> 6;
    const int quad = lane >> 4;
    const int l15  = lane & 15;
    const int h    = blockIdx.x % H;
    const int t0   = (blockIdx.x / H) * 64;

    if (tid <= NSEG) { sCuQ[tid] = cuq[tid]; sCuK[tid] = cuk[tid]; }
    __syncthreads();

    int qrow = t0 + 16 * w + l15; if (qrow >= T) qrow = T - 1;
    const float* qp = Q + ((size_t)qrow * H + h) * D + quad * 8;
    short8v aQ0, aQ1;
    {
        float4 a = *(const float4*)(qp);
        float4 b = *(const float4*)(qp + 4);
        float4 c = *(const float4*)(qp + 32);
        float4 e = *(const float4*)(qp + 36);
        aQ0[0]=f2bf(a.x*0.125f); aQ0[1]=f2bf(a.y*0.125f);
        aQ0[2]=f2bf(a.z*0.125f); aQ0[3]=f2bf(a.w*0.125f);
        aQ0[4]=f2bf(b.x*0.125f); aQ0[5]=f2bf(b.y*0.125f);
        aQ0[6]=f2bf(b.z*0.125f); aQ0[7]=f2bf(b.w*0.125f);
        aQ1[0]=f2bf(c.x*0.125f); aQ1[1]=f2bf(c.y*0.125f);
        aQ1[2]=f2bf(c.z*0.125f); aQ1[3]=f2bf(c.w*0.125f);
        aQ1[4]=f2bf(e.x*0.125f); aQ1[5]=f2bf(e.y*0.125f);
        aQ1[6]=f2bf(e.z*0.125f); aQ1[7]=f2bf(e.w*0.125f);
    }

    int segq[4];
    #pragma unroll
    for (int r = 0; r < 4; ++r) {
        int t = t0 + 16 * w + quad * 4 + r; if (t >= T) t = T - 1;
        int s = 0;
        while (s < NSEG - 1 && t >= sCuQ[s + 1]) ++s;
        segq[r] = s;
    }
    int k_start, k_end;
    {
        int tA = t0; if (tA >= T) tA = T - 1;
        int tB = t0 + 63; if (tB >= T) tB = T - 1;
        int sA = 0; while (sA < NSEG - 1 && tA >= sCuQ[sA + 1]) ++sA;
        int sB = 0; while (sB < NSEG - 1 && tB >= sCuQ[sB + 1]) ++sB;
        k_start = sCuK[sA];
        k_end   = sCuK[sB + 1];
    }

    floatx4 o[4];
    #pragma unroll
    for (int nt = 0; nt < 4; ++nt) o[nt] = (floatx4){0.f, 0.f, 0.f, 0.f};
    float l_r[4] = {0.f, 0.f, 0.f, 0.f};

    for (int kc = k_start; kc < k_end; kc += BK) {
        __syncthreads();
        for (int i = tid; i < BK * D / 4; i += 256) {
            int k = i >> 4;
            int c = (i & 15) << 2;
            int kt = kc + k;
            float4 kv = {0,0,0,0}, vv = {0,0,0,0};
            if (kt < k_end) {
                kv = *(const float4*)&K[((size_t)kt * H + h) * D + c];
                vv = *(const float4*)&V[((size_t)kt * H + h) * D + c];
            }
            short4v ks;
            ks.x=f2bf(kv.x); ks.y=f2bf(kv.y); ks.z=f2bf(kv.z); ks.w=f2bf(kv.w);
            *(short4v*)&sK[k][c] = ks;
            sVT[c+0][k]=f2bf(vv.x); sVT[c+1][k]=f2bf(vv.y);
            sVT[c+2][k]=f2bf(vv.z); sVT[c+3][k]=f2bf(vv.w);
        }
        if (tid < BK) {
            int kt = kc + tid;
            int s = -1;
            if (kt < k_end) { s = 0; while (s < NSEG - 1 && kt >= sCuK[s + 1]) ++s; }
            sSegK[tid] = s;
        }
        __syncthreads();

        floatx4 sacc[4];
        #pragma unroll
        for (int nt = 0; nt < 4; ++nt) {
            sacc[nt] = (floatx4){-8.f, -8.f, -8.f, -8.f};
            short8v b0 = *(const short8v*)&sK[nt * 16 + l15][quad * 8];
            short8v b1 = *(const short8v*)&sK[nt * 16 + l15][32 + quad * 8];
            sacc[nt] = __builtin_amdgcn_mfma_f32_16x16x32_bf16(aQ0, b0, sacc[nt], 0, 0, 0);
            sacc[nt] = __builtin_amdgcn_mfma_f32_16x16x32_bf16(aQ1, b1, sacc[nt], 0, 0, 0);
        }
        #pragma unroll
        for (int nt = 0; nt < 4; ++nt) {
            int segk = sSegK[nt * 16 + l15];
            #pragma unroll
            for (int r = 0; r < 4; ++r) {
                float sc = (segk == segq[r]) ? sacc[nt][r] : -1e30f;
                float p  = __expf(sc);
                l_r[r] += p;
                sP[w][quad * 4 + r][nt * 16 + l15] = f2bf(p);
            }
        }
        short8v aP0 = *(const short8v*)&sP[w][l15][quad * 8];
        short8v aP1 = *(const short8v*)&sP[w][l15][32 + quad * 8];
        #pragma unroll
        for (int nt = 0; nt < 4; ++nt) {
            short8v b0 = *(const short8v*)&sVT[nt * 16 + l15][quad * 8];
            short8v b1 = *(const short8v*)&sVT[nt * 16 + l15][32 + quad * 8];
            o[nt] = __builtin_amdgcn_mfma_f32_16x16x32_bf16(aP0, b0, o[nt], 0, 0, 0);
            o[nt] = __builtin_amdgcn_mfma_f32_16x16x32_bf16(aP1, b1, o[nt], 0, 0, 0);
        }
    }

    #pragma unroll
    for (int off = 1; off < 16; off <<= 1)
        #pragma unroll
        for (int r = 0; r < 4; ++r)
            l_r[r] += __shfl_xor(l_r[r], off);

    #pragma unroll
    for (int r = 0; r < 4; ++r) {
        int trow = t0 + 16 * w + quad * 4 + r;
        if (trow < T) {
            float linv = 1.0f / l_r[r];
            float* op = O + ((size_t)trow * H + h) * D + l15;
            #pragma unroll
            for (int nt = 0; nt < 4; ++nt)
                op[nt * 16] = o[nt][r] * linv;
        }
    }
}

extern "C" void kernel_launch(void* const* d_in, const int* in_sizes, int n_in,
                              void* d_out, int out_size, void* d_ws, size_t ws_size,
                              hipStream_t stream) {
    const float* Q = (const float*)d_in[0];
    const float* K = (const float*)d_in[1];
    const float* V = (const float*)d_in[2];
    const int* cuq = (const int*)d_in[3];
    const int* cuk = (const int*)d_in[4];
    float* O = (float*)d_out;
    (void)n_in; (void)out_size;

    int T = in_sizes[0] / (H * D);
    size_t need = (size_t)2 * H * T * D * sizeof(short) + (size_t)T * sizeof(int);
    int nQB = T >> 6;

    if (ws_size >= need && (T & 63) == 0 && nQB <= 64) {
        short* Kb = (short*)d_ws;
        short* Vb = Kb + (size_t)H * T * D;
        int* segArr = (int*)(Vb + (size_t)H * T * D);
        hipLaunchKernelGGL(prepass_kv, dim3(H * nQB), dim3(256), 0, stream,
                           K, V, cuk, Kb, Vb, segArr, T);
        hipLaunchKernelGGL(varlen_attn7, dim3(nQB * H), dim3(256), 0, stream,
                           Q, Kb, Vb, segArr, cuq, cuk, O, T);
    } else {
        int nQT = (T + 63) / 64;
        hipLaunchKernelGGL(varlen_attn_fb, dim3(nQT * H), dim3(256), 0, stream,
                           Q, K, V, cuq, cuk, O, T);
    }
}